// Round 3
// baseline (546.841 us; speedup 1.0000x reference)
//
#include <hip/hip_runtime.h>
#include <hip/hip_bf16.h>
#include <stdint.h>

// B=4 S=2048 D=1024 H=2048 E=8 ; T = 8192 tokens, top-1 MoE.
// Inputs FLOAT32, output FLOAT32; GEMM compute in bf16 MFMA (fp32 accum).
// Pipeline: router(fp32, also emits xbf) -> scan -> scatter ->
// transpose+cvt W1,W2 -> gemm1(bf16,relu) -> gemm2(split-K 8-wave, scale+scatter)

typedef unsigned short bf16_t;
typedef short short8 __attribute__((ext_vector_type(8)));
typedef float f32x4 __attribute__((ext_vector_type(4)));

#define T_TOK 8192
#define DDIM 1024
#define HDIM 2048
#define NEXP 8
#define MAXTILES 72   // sum ceil(count_e/128) <= (8192 + 8*127)/128 = 71

__device__ __forceinline__ bf16_t f2b(float f) {
    unsigned int x = __builtin_bit_cast(unsigned int, f);
    unsigned int r = x + 0x7fffu + ((x >> 16) & 1u);   // RNE
    return (bf16_t)(r >> 16);
}
__device__ __forceinline__ void gld_lds16(const bf16_t* src, bf16_t* dst) {
    // per-lane global src, wave-uniform LDS base; lane L writes at dst + L*16B
    __builtin_amdgcn_global_load_lds((const __attribute__((address_space(1))) void*)src,
                                     (__attribute__((address_space(3))) void*)dst, 16, 0, 0);
}

// ---------------- router: one wave per token (fp32), also converts x->bf16 ----------------
__global__ __launch_bounds__(256) void router_kernel(
    const float* __restrict__ x, const float* __restrict__ Wr,
    const float* __restrict__ br, int* __restrict__ expert_id,
    float* __restrict__ gate, int* __restrict__ counts,
    bf16_t* __restrict__ xbf) {
    int wave = threadIdx.x >> 6, lane = threadIdx.x & 63;
    int t = blockIdx.x * 4 + wave;
    const float* xt = x + (size_t)t * DDIM + lane * 16;
    float xv[16];
#pragma unroll
    for (int q = 0; q < 4; q++) {
        float4 f = *(const float4*)(xt + q * 4);
        xv[q * 4 + 0] = f.x; xv[q * 4 + 1] = f.y;
        xv[q * 4 + 2] = f.z; xv[q * 4 + 3] = f.w;
    }
    // emit bf16 copy of x (fused cvt)
    bf16_t tmp[16];
#pragma unroll
    for (int i = 0; i < 16; i++) tmp[i] = f2b(xv[i]);
    *(uint4*)(xbf + (size_t)t * DDIM + lane * 16)     = *(uint4*)&tmp[0];
    *(uint4*)(xbf + (size_t)t * DDIM + lane * 16 + 8) = *(uint4*)&tmp[8];

    float acc[NEXP];
#pragma unroll
    for (int e = 0; e < NEXP; e++) acc[e] = 0.f;
#pragma unroll
    for (int i = 0; i < 16; i++) {
        const float* wr = Wr + (size_t)(lane * 16 + i) * NEXP;
#pragma unroll
        for (int e = 0; e < NEXP; e++) acc[e] += xv[i] * wr[e];
    }
#pragma unroll
    for (int off = 32; off; off >>= 1)
#pragma unroll
        for (int e = 0; e < NEXP; e++) acc[e] += __shfl_xor(acc[e], off);
    if (lane == 0) {
        float l[NEXP];
#pragma unroll
        for (int e = 0; e < NEXP; e++) l[e] = acc[e] + br[e];
        int best = 0; float bm = l[0];
#pragma unroll
        for (int e = 1; e < NEXP; e++) if (l[e] > bm) { bm = l[e]; best = e; }
        float s = 0.f;
#pragma unroll
        for (int e = 0; e < NEXP; e++) s += __expf(l[e] - bm);
        expert_id[t] = best;
        gate[t] = 1.0f / s;      // softmax prob of the argmax expert
        atomicAdd(&counts[best], 1);
    }
}

// ---------------- scan: 128-aligned segment offsets + tile->expert map ----------------
__global__ __launch_bounds__(64) void scan_kernel(const int* __restrict__ counts,
                                                  int* __restrict__ pad_off,
                                                  int* __restrict__ tile_expert) {
    if (threadIdx.x == 0) {
        int rowoff = 0, t = 0;
        for (int e = 0; e < NEXP; e++) {
            pad_off[e] = rowoff;
            int nt = (counts[e] + 127) >> 7;
            rowoff += nt << 7;
            for (int i = 0; i < nt; i++) tile_expert[t++] = e;
        }
        while (t < MAXTILES) tile_expert[t++] = -1;
    }
}

// ---------------- scatter: build row->token maps ----------------
__global__ __launch_bounds__(256) void scatter_kernel(
    const int* __restrict__ expert_id, const float* __restrict__ gate,
    const int* __restrict__ pad_off, int* __restrict__ cursor,
    int* __restrict__ tok_of_row, float* __restrict__ gate_of_row) {
    int t = blockIdx.x * 256 + threadIdx.x;
    int e = expert_id[t];
    int p = atomicAdd(&cursor[e], 1);
    int row = pad_off[e] + p;
    tok_of_row[row] = t;
    gate_of_row[row] = gate[t];
}

// ---------------- fp32 -> bf16 tiled transpose: in [z][R][C] -> out [z][C][R] ----------------
__global__ __launch_bounds__(256) void transpose_kernel(const float* __restrict__ in,
                                                        bf16_t* __restrict__ out,
                                                        int R, int C) {
    __shared__ bf16_t tile[64][72];   // +8 pad: rows stay 16B-aligned, no pow2 bank stride
    int z = blockIdx.z;
    const float* inp = in + (size_t)z * R * C;
    bf16_t* outp = out + (size_t)z * R * C;
    int r0 = blockIdx.y * 64, c0 = blockIdx.x * 64;
    int tid = threadIdx.x;
#pragma unroll
    for (int v = tid; v < 1024; v += 256) {     // 64x64 floats, 4/thread-iter
        int r = v >> 4, c = (v & 15) * 4;
        float4 f = *(const float4*)(inp + (size_t)(r0 + r) * C + c0 + c);
        tile[r][c + 0] = f2b(f.x); tile[r][c + 1] = f2b(f.y);
        tile[r][c + 2] = f2b(f.z); tile[r][c + 3] = f2b(f.w);
    }
    __syncthreads();
#pragma unroll
    for (int v = tid; v < 512; v += 256) {
        int c = v >> 3, r = (v & 7) * 8;
        bf16_t tmp[8];
#pragma unroll
        for (int i = 0; i < 8; i++) tmp[i] = tile[r + i][c];
        *(uint4*)(outp + (size_t)(c0 + c) * R + r0 + r) = *(uint4*)tmp;
    }
}

// ---------------- GEMM1: h[row][H] = relu(xbf[tok[row]] @ W1t[e]^T + b1[e]) ----------------
// W1t: [E][H][D] (K-contiguous rows). grid (H/128, MAXTILES), block 256 (4 waves).
__global__ __launch_bounds__(256) void gemm1_kernel(
    const bf16_t* __restrict__ x, const bf16_t* __restrict__ W1t,
    const float* __restrict__ b1, const int* __restrict__ tile_expert,
    const int* __restrict__ tok_of_row, bf16_t* __restrict__ hbuf) {
    constexpr int K = DDIM, N = HDIM;
    int tile_n = blockIdx.x, tile_m = blockIdx.y;
    int e = tile_expert[tile_m];
    if (e < 0) return;
    __shared__ bf16_t lA[128 * 64];
    __shared__ bf16_t lB[128 * 64];
    int tid = threadIdx.x, wave = tid >> 6, lane = tid & 63;
    const bf16_t* asrc[4]; const bf16_t* bsrc[4];
#pragma unroll
    for (int c = 0; c < 4; c++) {
        int rr = wave * 32 + c * 8 + (lane >> 3);
        int tok = tok_of_row[tile_m * 128 + rr];
        if (tok < 0) tok = 0;   // padded row: read any valid row; store masked in gemm2
        asrc[c] = x + (size_t)tok * K + (lane & 7) * 8;
        bsrc[c] = W1t + (size_t)e * N * K + (size_t)(tile_n * 128 + rr) * K + (lane & 7) * 8;
    }
    f32x4 acc[4][4];
#pragma unroll
    for (int i = 0; i < 4; i++)
#pragma unroll
        for (int j = 0; j < 4; j++) acc[i][j] = {0.f, 0.f, 0.f, 0.f};
    int wm = wave >> 1, wn = wave & 1;
    int lm = lane & 15, quad = lane >> 4;
    for (int k0 = 0; k0 < K; k0 += 64) {
        __syncthreads();
#pragma unroll
        for (int c = 0; c < 4; c++) {
            gld_lds16(asrc[c] + k0, &lA[(wave * 32 + c * 8) * 64]);
            gld_lds16(bsrc[c] + k0, &lB[(wave * 32 + c * 8) * 64]);
        }
        __syncthreads();
#pragma unroll
        for (int kk = 0; kk < 2; kk++) {
            short8 a[4], b[4];
#pragma unroll
            for (int i = 0; i < 4; i++)
                a[i] = *(const short8*)&lA[(wm * 64 + i * 16 + lm) * 64 + kk * 32 + quad * 8];
#pragma unroll
            for (int j = 0; j < 4; j++)
                b[j] = *(const short8*)&lB[(wn * 64 + j * 16 + lm) * 64 + kk * 32 + quad * 8];
#pragma unroll
            for (int i = 0; i < 4; i++)
#pragma unroll
                for (int j = 0; j < 4; j++)
                    acc[i][j] = __builtin_amdgcn_mfma_f32_16x16x32_bf16(a[i], b[j], acc[i][j], 0, 0, 0);
        }
    }
#pragma unroll
    for (int j = 0; j < 4; j++) {
        int col = tile_n * 128 + wn * 64 + j * 16 + lm;
        float bias = b1[e * N + col];
#pragma unroll
        for (int i = 0; i < 4; i++)
#pragma unroll
            for (int r = 0; r < 4; r++) {
                int row = tile_m * 128 + wm * 64 + i * 16 + quad * 4 + r;
                float v = acc[i][j][r] + bias;
                hbuf[(size_t)row * N + col] = f2b(fmaxf(v, 0.f));
            }
    }
}

// ---------------- GEMM2 (split-K, 8 waves): out[tok[row]] = (h[row]@W2t[e]^T + b2[e])*gate ----
// W2t: [E][D][H]. grid (D/128, MAXTILES), block 512. Waves 0-3: K half 0; waves 4-7: K half 1.
// Combine in LDS, fp32 scatter store.
__global__ __launch_bounds__(512) void gemm2_kernel(
    const bf16_t* __restrict__ hbuf, const bf16_t* __restrict__ W2t,
    const float* __restrict__ b2, const int* __restrict__ tile_expert,
    const int* __restrict__ tok_of_row, const float* __restrict__ gate_of_row,
    float* __restrict__ out) {
    constexpr int K = HDIM, N = DDIM, KH = K / 2;   // 1024 per half
    int tile_n = blockIdx.x, tile_m = blockIdx.y;
    int e = tile_expert[tile_m];
    if (e < 0) return;
    __shared__ bf16_t smem[4 * 128 * 64];   // 64 KiB: lA/lB per half; reused as fp32 combine
    int tid = threadIdx.x, wave = tid >> 6, lane = tid & 63;
    int half = wave >> 2, w4 = wave & 3;
    bf16_t* lA = smem + half * (128 * 64);
    bf16_t* lB = smem + (2 + half) * (128 * 64);
    const bf16_t* asrc[4]; const bf16_t* bsrc[4];
    size_t kbase = (size_t)half * KH;
#pragma unroll
    for (int c = 0; c < 4; c++) {
        int rr = w4 * 32 + c * 8 + (lane >> 3);
        asrc[c] = hbuf + (size_t)(tile_m * 128 + rr) * K + kbase + (lane & 7) * 8;
        bsrc[c] = W2t + (size_t)e * N * K + (size_t)(tile_n * 128 + rr) * K + kbase + (lane & 7) * 8;
    }
    f32x4 acc[4][4];
#pragma unroll
    for (int i = 0; i < 4; i++)
#pragma unroll
        for (int j = 0; j < 4; j++) acc[i][j] = {0.f, 0.f, 0.f, 0.f};
    int wm = w4 >> 1, wn = w4 & 1;
    int lm = lane & 15, quad = lane >> 4;
    for (int k0 = 0; k0 < KH; k0 += 64) {
        __syncthreads();
#pragma unroll
        for (int c = 0; c < 4; c++) {
            gld_lds16(asrc[c] + k0, &lA[(w4 * 32 + c * 8) * 64]);
            gld_lds16(bsrc[c] + k0, &lB[(w4 * 32 + c * 8) * 64]);
        }
        __syncthreads();
#pragma unroll
        for (int kk = 0; kk < 2; kk++) {
            short8 a[4], b[4];
#pragma unroll
            for (int i = 0; i < 4; i++)
                a[i] = *(const short8*)&lA[(wm * 64 + i * 16 + lm) * 64 + kk * 32 + quad * 8];
#pragma unroll
            for (int j = 0; j < 4; j++)
                b[j] = *(const short8*)&lB[(wn * 64 + j * 16 + lm) * 64 + kk * 32 + quad * 8];
#pragma unroll
            for (int i = 0; i < 4; i++)
#pragma unroll
                for (int j = 0; j < 4; j++)
                    acc[i][j] = __builtin_amdgcn_mfma_f32_16x16x32_bf16(a[i], b[j], acc[i][j], 0, 0, 0);
        }
    }
    // combine halves in LDS (128x128 fp32 = 64 KiB overlays smem)
    __syncthreads();
    float* cb = (float*)smem;
    if (half == 1) {
#pragma unroll
        for (int j = 0; j < 4; j++)
#pragma unroll
            for (int i = 0; i < 4; i++)
#pragma unroll
                for (int r = 0; r < 4; r++)
                    cb[(wm * 64 + i * 16 + quad * 4 + r) * 128 + wn * 64 + j * 16 + lm] =
                        acc[i][j][r];
    }
    __syncthreads();
    if (half == 0) {
#pragma unroll
        for (int j = 0; j < 4; j++) {
            int coll = wn * 64 + j * 16 + lm;
            int col = tile_n * 128 + coll;
            float bias = b2[e * N + col];
#pragma unroll
            for (int i = 0; i < 4; i++)
#pragma unroll
                for (int r = 0; r < 4; r++) {
                    int rowl = wm * 64 + i * 16 + quad * 4 + r;
                    int row = tile_m * 128 + rowl;
                    int tok = tok_of_row[row];
                    if (tok >= 0) {
                        float v = (acc[i][j][r] + cb[rowl * 128 + coll] + bias) * gate_of_row[row];
                        out[(size_t)tok * N + col] = v;   // fp32 store
                    }
                }
        }
    }
}

extern "C" void kernel_launch(void* const* d_in, const int* in_sizes, int n_in,
                              void* d_out, int out_size, void* d_ws, size_t ws_size,
                              hipStream_t stream) {
    const float* x  = (const float*)d_in[0];
    const float* Wr = (const float*)d_in[1];
    const float* br = (const float*)d_in[2];
    const float* W1 = (const float*)d_in[3];
    const float* b1 = (const float*)d_in[4];
    const float* W2 = (const float*)d_in[5];
    const float* b2 = (const float*)d_in[6];
    float* out = (float*)d_out;
    char* ws = (char*)d_ws;

    // ws layout (bytes)
    int*    counts      = (int*)(ws + 0);       // 32 B (zeroed)
    int*    cursor      = (int*)(ws + 32);      // 32 B (zeroed)
    int*    pad_off     = (int*)(ws + 64);      // 32 B
    int*    tile_expert = (int*)(ws + 96);      // 288 B
    int*    expert_id   = (int*)(ws + 512);     // 32 KiB
    float*  gate        = (float*)(ws + 33280); // 32 KiB
    int*    tok_of_row  = (int*)(ws + 66048);   // 36 KiB (0xFF => -1)
    float*  gate_of_row = (float*)(ws + 102912);// 36 KiB
    bf16_t* hbuf        = (bf16_t*)(ws + 139776);    // 9216*2048*2 = 37,748,736
    bf16_t* W1t         = (bf16_t*)(ws + 37888512);  // 8*2048*1024*2 = 33,554,432
    bf16_t* W2t         = (bf16_t*)(ws + 71442944);  // 8*1024*2048*2 = 33,554,432
    bf16_t* xbf         = (bf16_t*)(ws + 104997376); // 8192*1024*2  = 16,777,216
    // total ~122 MB

    hipMemsetAsync(counts, 0, 64, stream);                       // counts + cursor
    hipMemsetAsync(tok_of_row, 0xFF, (MAXTILES * 128) * 4, stream);

    router_kernel<<<T_TOK / 4, 256, 0, stream>>>(x, Wr, br, expert_id, gate, counts, xbf);
    scan_kernel<<<1, 64, 0, stream>>>(counts, pad_off, tile_expert);
    scatter_kernel<<<T_TOK / 256, 256, 0, stream>>>(expert_id, gate, pad_off, cursor,
                                                    tok_of_row, gate_of_row);
    transpose_kernel<<<dim3(HDIM / 64, DDIM / 64, NEXP), 256, 0, stream>>>(W1, W1t, DDIM, HDIM);
    transpose_kernel<<<dim3(DDIM / 64, HDIM / 64, NEXP), 256, 0, stream>>>(W2, W2t, HDIM, DDIM);
    gemm1_kernel<<<dim3(HDIM / 128, MAXTILES), 256, 0, stream>>>(xbf, W1t, b1, tile_expert,
                                                                 tok_of_row, hbuf);
    gemm2_kernel<<<dim3(DDIM / 128, MAXTILES), 512, 0, stream>>>(hbuf, W2t, b2, tile_expert,
                                                                 tok_of_row, gate_of_row, out);
}

// Round 4
// 508.316 us; speedup vs baseline: 1.0758x; 1.0758x over previous
//
#include <hip/hip_runtime.h>
#include <hip/hip_bf16.h>
#include <stdint.h>

// B=4 S=2048 D=1024 H=2048 E=8 ; T = 8192 tokens, top-1 MoE.
// Inputs FLOAT32, output FLOAT32; GEMM compute in bf16 MFMA (fp32 accum).
// Round 4: 64x128 GEMM tiles (grid-limited occupancy fix), fused transpose launch,
// scan kernel also inits tok_of_row. 7 dispatches total.

typedef unsigned short bf16_t;
typedef short short8 __attribute__((ext_vector_type(8)));
typedef float f32x4 __attribute__((ext_vector_type(4)));

#define T_TOK 8192
#define DDIM 1024
#define HDIM 2048
#define NEXP 8
#define MAXT64 136          // sum ceil(count_e/64) <= 8192/64 + 8 = 136
#define ROWSP (MAXT64 * 64) // 8704 padded row space

__device__ __forceinline__ bf16_t f2b(float f) {
    unsigned int x = __builtin_bit_cast(unsigned int, f);
    unsigned int r = x + 0x7fffu + ((x >> 16) & 1u);   // RNE
    return (bf16_t)(r >> 16);
}
__device__ __forceinline__ void gld_lds16(const bf16_t* src, bf16_t* dst) {
    // per-lane global src, wave-uniform LDS base; lane L writes at dst + L*16B
    __builtin_amdgcn_global_load_lds((const __attribute__((address_space(1))) void*)src,
                                     (__attribute__((address_space(3))) void*)dst, 16, 0, 0);
}

// ---------------- router: one wave per token (fp32), also converts x->bf16 ----------------
__global__ __launch_bounds__(256) void router_kernel(
    const float* __restrict__ x, const float* __restrict__ Wr,
    const float* __restrict__ br, int* __restrict__ expert_id,
    float* __restrict__ gate, int* __restrict__ counts,
    bf16_t* __restrict__ xbf) {
    int wave = threadIdx.x >> 6, lane = threadIdx.x & 63;
    int t = blockIdx.x * 4 + wave;
    const float* xt = x + (size_t)t * DDIM + lane * 16;
    float xv[16];
#pragma unroll
    for (int q = 0; q < 4; q++) {
        float4 f = *(const float4*)(xt + q * 4);
        xv[q * 4 + 0] = f.x; xv[q * 4 + 1] = f.y;
        xv[q * 4 + 2] = f.z; xv[q * 4 + 3] = f.w;
    }
    bf16_t tmp[16];
#pragma unroll
    for (int i = 0; i < 16; i++) tmp[i] = f2b(xv[i]);
    *(uint4*)(xbf + (size_t)t * DDIM + lane * 16)     = *(uint4*)&tmp[0];
    *(uint4*)(xbf + (size_t)t * DDIM + lane * 16 + 8) = *(uint4*)&tmp[8];

    float acc[NEXP];
#pragma unroll
    for (int e = 0; e < NEXP; e++) acc[e] = 0.f;
#pragma unroll
    for (int i = 0; i < 16; i++) {
        const float* wr = Wr + (size_t)(lane * 16 + i) * NEXP;
#pragma unroll
        for (int e = 0; e < NEXP; e++) acc[e] += xv[i] * wr[e];
    }
#pragma unroll
    for (int off = 32; off; off >>= 1)
#pragma unroll
        for (int e = 0; e < NEXP; e++) acc[e] += __shfl_xor(acc[e], off);
    if (lane == 0) {
        float l[NEXP];
#pragma unroll
        for (int e = 0; e < NEXP; e++) l[e] = acc[e] + br[e];
        int best = 0; float bm = l[0];
#pragma unroll
        for (int e = 1; e < NEXP; e++) if (l[e] > bm) { bm = l[e]; best = e; }
        float s = 0.f;
#pragma unroll
        for (int e = 0; e < NEXP; e++) s += __expf(l[e] - bm);
        expert_id[t] = best;
        gate[t] = 1.0f / s;      // softmax prob of the argmax expert
        atomicAdd(&counts[best], 1);
    }
}

// ---------------- scan: 64-aligned segment offsets + 64-tile->expert map + row init --------
__global__ __launch_bounds__(256) void scan_kernel(const int* __restrict__ counts,
                                                   int* __restrict__ pad_off,
                                                   int* __restrict__ tile_expert,
                                                   int* __restrict__ tok_of_row) {
    for (int i = threadIdx.x; i < ROWSP; i += 256) tok_of_row[i] = -1;
    if (threadIdx.x == 0) {
        int rowoff = 0, t = 0;
        for (int e = 0; e < NEXP; e++) {
            pad_off[e] = rowoff;
            int nt = (counts[e] + 63) >> 6;
            rowoff += nt << 6;
            for (int i = 0; i < nt; i++) tile_expert[t++] = e;
        }
        while (t < MAXT64) tile_expert[t++] = -1;
    }
}

// ---------------- scatter: build row->token maps ----------------
__global__ __launch_bounds__(256) void scatter_kernel(
    const int* __restrict__ expert_id, const float* __restrict__ gate,
    const int* __restrict__ pad_off, int* __restrict__ cursor,
    int* __restrict__ tok_of_row, float* __restrict__ gate_of_row) {
    int t = blockIdx.x * 256 + threadIdx.x;
    int e = expert_id[t];
    int p = atomicAdd(&cursor[e], 1);
    int row = pad_off[e] + p;
    tok_of_row[row] = t;
    gate_of_row[row] = gate[t];
}

// ------------- fused fp32->bf16 transpose of W1 (z<8) and W2 (z>=8) -------------
// in [z][R][C] -> out [z][C][R]; R*C = 2M for both, 512 64x64 tiles per z.
__global__ __launch_bounds__(256) void transpose_all_kernel(
    const float* __restrict__ W1, const float* __restrict__ W2,
    bf16_t* __restrict__ W1t, bf16_t* __restrict__ W2t) {
    __shared__ bf16_t tile[64][72];   // +8 pad: no pow2 bank stride
    int z = blockIdx.z;
    const float* inp; bf16_t* outp; int R, C;
    if (z < 8) { inp = W1 + (size_t)z * DDIM * HDIM; outp = W1t + (size_t)z * DDIM * HDIM;
                 R = DDIM; C = HDIM; }
    else       { inp = W2 + (size_t)(z - 8) * HDIM * DDIM; outp = W2t + (size_t)(z - 8) * HDIM * DDIM;
                 R = HDIM; C = DDIM; }
    int ctiles = C >> 6;
    int cx = blockIdx.x % ctiles, ry = blockIdx.x / ctiles;
    int r0 = ry * 64, c0 = cx * 64;
    int tid = threadIdx.x;
#pragma unroll
    for (int v = tid; v < 1024; v += 256) {     // 64x64 floats, 4/thread-iter
        int r = v >> 4, c = (v & 15) * 4;
        float4 f = *(const float4*)(inp + (size_t)(r0 + r) * C + c0 + c);
        tile[r][c + 0] = f2b(f.x); tile[r][c + 1] = f2b(f.y);
        tile[r][c + 2] = f2b(f.z); tile[r][c + 3] = f2b(f.w);
    }
    __syncthreads();
#pragma unroll
    for (int v = tid; v < 512; v += 256) {
        int c = v >> 3, r = (v & 7) * 8;
        bf16_t tmp[8];
#pragma unroll
        for (int i = 0; i < 8; i++) tmp[i] = tile[r + i][c];
        *(uint4*)(outp + (size_t)(c0 + c) * R + r0 + r) = *(uint4*)tmp;
    }
}

// ---------------- GEMM1: h[row][H] = relu(xbf[tok[row]] @ W1t[e]^T + b1[e]) ----------------
// 64x128 tile. W1t: [E][H][D]. grid (H/128, MAXT64), block 256 (4 waves, 2x2 wave grid).
__global__ __launch_bounds__(256) void gemm1_kernel(
    const bf16_t* __restrict__ x, const bf16_t* __restrict__ W1t,
    const float* __restrict__ b1, const int* __restrict__ tile_expert,
    const int* __restrict__ tok_of_row, bf16_t* __restrict__ hbuf) {
    constexpr int K = DDIM, N = HDIM;
    int tile_n = blockIdx.x, tile_m = blockIdx.y;
    int e = tile_expert[tile_m];
    if (e < 0) return;
    __shared__ bf16_t lA[64 * 64];    // 8 KiB
    __shared__ bf16_t lB[128 * 64];   // 16 KiB
    int tid = threadIdx.x, wave = tid >> 6, lane = tid & 63;
    const bf16_t* asrc[2]; const bf16_t* bsrc[4];
#pragma unroll
    for (int c = 0; c < 2; c++) {
        int rr = wave * 16 + c * 8 + (lane >> 3);
        int tok = tok_of_row[tile_m * 64 + rr];
        if (tok < 0) tok = 0;   // padded row: read any valid row; masked downstream
        asrc[c] = x + (size_t)tok * K + (lane & 7) * 8;
    }
#pragma unroll
    for (int c = 0; c < 4; c++) {
        int rr = wave * 32 + c * 8 + (lane >> 3);
        bsrc[c] = W1t + (size_t)e * N * K + (size_t)(tile_n * 128 + rr) * K + (lane & 7) * 8;
    }
    f32x4 acc[2][4];
#pragma unroll
    for (int i = 0; i < 2; i++)
#pragma unroll
        for (int j = 0; j < 4; j++) acc[i][j] = {0.f, 0.f, 0.f, 0.f};
    int wm = wave >> 1, wn = wave & 1;
    int lm = lane & 15, quad = lane >> 4;
    for (int k0 = 0; k0 < K; k0 += 64) {
        __syncthreads();
#pragma unroll
        for (int c = 0; c < 2; c++)
            gld_lds16(asrc[c] + k0, &lA[(wave * 16 + c * 8) * 64]);
#pragma unroll
        for (int c = 0; c < 4; c++)
            gld_lds16(bsrc[c] + k0, &lB[(wave * 32 + c * 8) * 64]);
        __syncthreads();
#pragma unroll
        for (int kk = 0; kk < 2; kk++) {
            short8 a[2], b[4];
#pragma unroll
            for (int i = 0; i < 2; i++)
                a[i] = *(const short8*)&lA[(wm * 32 + i * 16 + lm) * 64 + kk * 32 + quad * 8];
#pragma unroll
            for (int j = 0; j < 4; j++)
                b[j] = *(const short8*)&lB[(wn * 64 + j * 16 + lm) * 64 + kk * 32 + quad * 8];
#pragma unroll
            for (int i = 0; i < 2; i++)
#pragma unroll
                for (int j = 0; j < 4; j++)
                    acc[i][j] = __builtin_amdgcn_mfma_f32_16x16x32_bf16(a[i], b[j], acc[i][j], 0, 0, 0);
        }
    }
#pragma unroll
    for (int j = 0; j < 4; j++) {
        int col = tile_n * 128 + wn * 64 + j * 16 + lm;
        float bias = b1[e * N + col];
#pragma unroll
        for (int i = 0; i < 2; i++)
#pragma unroll
            for (int r = 0; r < 4; r++) {
                int row = tile_m * 64 + wm * 32 + i * 16 + quad * 4 + r;
                float v = acc[i][j][r] + bias;
                hbuf[(size_t)row * N + col] = f2b(fmaxf(v, 0.f));
            }
    }
}

// ---------------- GEMM2: out[tok[row]] = (h[row]@W2t[e]^T + b2[e])*gate[row] ----------------
// 64x128 tile. W2t: [E][D][H]. grid (D/128, MAXT64), block 256. fp32 scatter store.
__global__ __launch_bounds__(256) void gemm2_kernel(
    const bf16_t* __restrict__ hbuf, const bf16_t* __restrict__ W2t,
    const float* __restrict__ b2, const int* __restrict__ tile_expert,
    const int* __restrict__ tok_of_row, const float* __restrict__ gate_of_row,
    float* __restrict__ out) {
    constexpr int K = HDIM, N = DDIM;
    int tile_n = blockIdx.x, tile_m = blockIdx.y;
    int e = tile_expert[tile_m];
    if (e < 0) return;
    __shared__ bf16_t lA[64 * 64];
    __shared__ bf16_t lB[128 * 64];
    int tid = threadIdx.x, wave = tid >> 6, lane = tid & 63;
    const bf16_t* asrc[2]; const bf16_t* bsrc[4];
#pragma unroll
    for (int c = 0; c < 2; c++) {
        int rr = wave * 16 + c * 8 + (lane >> 3);
        asrc[c] = hbuf + (size_t)(tile_m * 64 + rr) * K + (lane & 7) * 8;
    }
#pragma unroll
    for (int c = 0; c < 4; c++) {
        int rr = wave * 32 + c * 8 + (lane >> 3);
        bsrc[c] = W2t + (size_t)e * N * K + (size_t)(tile_n * 128 + rr) * K + (lane & 7) * 8;
    }
    f32x4 acc[2][4];
#pragma unroll
    for (int i = 0; i < 2; i++)
#pragma unroll
        for (int j = 0; j < 4; j++) acc[i][j] = {0.f, 0.f, 0.f, 0.f};
    int wm = wave >> 1, wn = wave & 1;
    int lm = lane & 15, quad = lane >> 4;
    for (int k0 = 0; k0 < K; k0 += 64) {
        __syncthreads();
#pragma unroll
        for (int c = 0; c < 2; c++)
            gld_lds16(asrc[c] + k0, &lA[(wave * 16 + c * 8) * 64]);
#pragma unroll
        for (int c = 0; c < 4; c++)
            gld_lds16(bsrc[c] + k0, &lB[(wave * 32 + c * 8) * 64]);
        __syncthreads();
#pragma unroll
        for (int kk = 0; kk < 2; kk++) {
            short8 a[2], b[4];
#pragma unroll
            for (int i = 0; i < 2; i++)
                a[i] = *(const short8*)&lA[(wm * 32 + i * 16 + lm) * 64 + kk * 32 + quad * 8];
#pragma unroll
            for (int j = 0; j < 4; j++)
                b[j] = *(const short8*)&lB[(wn * 64 + j * 16 + lm) * 64 + kk * 32 + quad * 8];
#pragma unroll
            for (int i = 0; i < 2; i++)
#pragma unroll
                for (int j = 0; j < 4; j++)
                    acc[i][j] = __builtin_amdgcn_mfma_f32_16x16x32_bf16(a[i], b[j], acc[i][j], 0, 0, 0);
        }
    }
#pragma unroll
    for (int j = 0; j < 4; j++) {
        int col = tile_n * 128 + wn * 64 + j * 16 + lm;
        float bias = b2[e * N + col];
#pragma unroll
        for (int i = 0; i < 2; i++)
#pragma unroll
            for (int r = 0; r < 4; r++) {
                int row = tile_m * 64 + wm * 32 + i * 16 + quad * 4 + r;
                int tok = tok_of_row[row];
                if (tok >= 0) {
                    float v = (acc[i][j][r] + bias) * gate_of_row[row];
                    out[(size_t)tok * N + col] = v;   // fp32 store
                }
            }
    }
}

extern "C" void kernel_launch(void* const* d_in, const int* in_sizes, int n_in,
                              void* d_out, int out_size, void* d_ws, size_t ws_size,
                              hipStream_t stream) {
    const float* x  = (const float*)d_in[0];
    const float* Wr = (const float*)d_in[1];
    const float* br = (const float*)d_in[2];
    const float* W1 = (const float*)d_in[3];
    const float* b1 = (const float*)d_in[4];
    const float* W2 = (const float*)d_in[5];
    const float* b2 = (const float*)d_in[6];
    float* out = (float*)d_out;
    char* ws = (char*)d_ws;

    // ws layout (bytes)
    int*    counts      = (int*)(ws + 0);        // 32 B (zeroed)
    int*    cursor      = (int*)(ws + 32);       // 32 B (zeroed)
    int*    pad_off     = (int*)(ws + 64);       // 32 B
    int*    tile_expert = (int*)(ws + 96);       // 544 B (MAXT64)
    int*    expert_id   = (int*)(ws + 1024);     // 32 KiB
    float*  gate        = (float*)(ws + 33792);  // 32 KiB
    int*    tok_of_row  = (int*)(ws + 66560);    // 34816 B
    float*  gate_of_row = (float*)(ws + 101376); // 34816 B
    bf16_t* hbuf        = (bf16_t*)(ws + 136192);    // 8704*2048*2 = 35,651,584
    bf16_t* W1t         = (bf16_t*)(ws + 35787776);  // 33,554,432
    bf16_t* W2t         = (bf16_t*)(ws + 69342208);  // 33,554,432
    bf16_t* xbf         = (bf16_t*)(ws + 102896640); // 16,777,216 -> ends 119,673,856
    // total ~120 MB

    hipMemsetAsync(counts, 0, 64, stream);   // counts + cursor

    router_kernel<<<T_TOK / 4, 256, 0, stream>>>(x, Wr, br, expert_id, gate, counts, xbf);
    scan_kernel<<<1, 256, 0, stream>>>(counts, pad_off, tile_expert, tok_of_row);
    scatter_kernel<<<T_TOK / 256, 256, 0, stream>>>(expert_id, gate, pad_off, cursor,
                                                    tok_of_row, gate_of_row);
    transpose_all_kernel<<<dim3(512, 1, 16), 256, 0, stream>>>(W1, W2, W1t, W2t);
    gemm1_kernel<<<dim3(HDIM / 128, MAXT64), 256, 0, stream>>>(xbf, W1t, b1, tile_expert,
                                                               tok_of_row, hbuf);
    gemm2_kernel<<<dim3(DDIM / 128, MAXT64), 256, 0, stream>>>(hbuf, W2t, b2, tile_expert,
                                                               tok_of_row, gate_of_row, out);
}

// Round 5
// 413.614 us; speedup vs baseline: 1.3221x; 1.2290x over previous
//
#include <hip/hip_runtime.h>
#include <hip/hip_bf16.h>
#include <stdint.h>

// B=4 S=2048 D=1024 H=2048 E=8 ; T = 8192 tokens, top-1 MoE.
// Inputs FLOAT32, output FLOAT32; GEMM compute in bf16 MFMA (fp32 accum).
// Round 5: register-resident-Wr router (fixes L1-serialized Wr loads),
// LDS histogram for counts. GEMMs/transpose unchanged from round 4.

typedef unsigned short bf16_t;
typedef short short8 __attribute__((ext_vector_type(8)));
typedef float f32x4 __attribute__((ext_vector_type(4)));

#define T_TOK 8192
#define DDIM 1024
#define HDIM 2048
#define NEXP 8
#define MAXT64 136          // sum ceil(count_e/64) <= 8192/64 + 8 = 136
#define ROWSP (MAXT64 * 64) // 8704 padded row space

__device__ __forceinline__ bf16_t f2b(float f) {
    unsigned int x = __builtin_bit_cast(unsigned int, f);
    unsigned int r = x + 0x7fffu + ((x >> 16) & 1u);   // RNE
    return (bf16_t)(r >> 16);
}
__device__ __forceinline__ void gld_lds16(const bf16_t* src, bf16_t* dst) {
    // per-lane global src, wave-uniform LDS base; lane L writes at dst + L*16B
    __builtin_amdgcn_global_load_lds((const __attribute__((address_space(1))) void*)src,
                                     (__attribute__((address_space(3))) void*)dst, 16, 0, 0);
}

// ---------------- router: Wr in VGPRs, 4 tokens/wave, fused x->bf16 ----------------
// grid 512 x 256 threads (4 waves); wave w handles tokens (blockIdx*4+w)*4 .. +3.
// Lane l holds Wr rows {i*256 + l*4 + j : i=0..3, j=0..3}, all 8 cols (128 VGPRs).
__global__ __launch_bounds__(256) void router_kernel(
    const float* __restrict__ x, const float* __restrict__ Wr,
    const float* __restrict__ br, int* __restrict__ expert_id,
    float* __restrict__ gate, int* __restrict__ counts,
    bf16_t* __restrict__ xbf) {
    __shared__ int hcnt[NEXP];
    int tid = threadIdx.x, wave = tid >> 6, lane = tid & 63;
    if (tid < NEXP) hcnt[tid] = 0;
    __syncthreads();

    float w[4][4][NEXP];
#pragma unroll
    for (int i = 0; i < 4; i++)
#pragma unroll
        for (int j = 0; j < 4; j++) {
            const float* p = Wr + (size_t)(i * 256 + lane * 4 + j) * NEXP;
            float4 a = *(const float4*)p;
            float4 b = *(const float4*)(p + 4);
            w[i][j][0] = a.x; w[i][j][1] = a.y; w[i][j][2] = a.z; w[i][j][3] = a.w;
            w[i][j][4] = b.x; w[i][j][5] = b.y; w[i][j][6] = b.z; w[i][j][7] = b.w;
        }

    int t0 = (blockIdx.x * 4 + wave) * 4;
#pragma unroll
    for (int tt = 0; tt < 4; tt++) {
        int t = t0 + tt;
        float acc[NEXP];
#pragma unroll
        for (int e = 0; e < NEXP; e++) acc[e] = 0.f;
#pragma unroll
        for (int i = 0; i < 4; i++) {
            const float* xp = x + (size_t)t * DDIM + i * 256 + lane * 4;
            float4 xv = *(const float4*)xp;
            bf16_t tmp[4] = {f2b(xv.x), f2b(xv.y), f2b(xv.z), f2b(xv.w)};
            *(uint2*)(xbf + (size_t)t * DDIM + i * 256 + lane * 4) = *(uint2*)tmp;
            float xs[4] = {xv.x, xv.y, xv.z, xv.w};
#pragma unroll
            for (int j = 0; j < 4; j++)
#pragma unroll
                for (int e = 0; e < NEXP; e++) acc[e] += xs[j] * w[i][j][e];
        }
#pragma unroll
        for (int off = 32; off; off >>= 1)
#pragma unroll
            for (int e = 0; e < NEXP; e++) acc[e] += __shfl_xor(acc[e], off);
        if (lane == 0) {
            float l[NEXP];
#pragma unroll
            for (int e = 0; e < NEXP; e++) l[e] = acc[e] + br[e];
            int best = 0; float bm = l[0];
#pragma unroll
            for (int e = 1; e < NEXP; e++) if (l[e] > bm) { bm = l[e]; best = e; }
            float s = 0.f;
#pragma unroll
            for (int e = 0; e < NEXP; e++) s += __expf(l[e] - bm);
            expert_id[t] = best;
            gate[t] = 1.0f / s;      // softmax prob of the argmax expert
            atomicAdd(&hcnt[best], 1);
        }
    }
    __syncthreads();
    if (tid < NEXP) atomicAdd(&counts[tid], hcnt[tid]);
}

// ---------------- scan: 64-aligned segment offsets + 64-tile->expert map + row init --------
__global__ __launch_bounds__(256) void scan_kernel(const int* __restrict__ counts,
                                                   int* __restrict__ pad_off,
                                                   int* __restrict__ tile_expert,
                                                   int* __restrict__ tok_of_row) {
    for (int i = threadIdx.x; i < ROWSP; i += 256) tok_of_row[i] = -1;
    if (threadIdx.x == 0) {
        int rowoff = 0, t = 0;
        for (int e = 0; e < NEXP; e++) {
            pad_off[e] = rowoff;
            int nt = (counts[e] + 63) >> 6;
            rowoff += nt << 6;
            for (int i = 0; i < nt; i++) tile_expert[t++] = e;
        }
        while (t < MAXT64) tile_expert[t++] = -1;
    }
}

// ---------------- scatter: build row->token maps ----------------
__global__ __launch_bounds__(256) void scatter_kernel(
    const int* __restrict__ expert_id, const float* __restrict__ gate,
    const int* __restrict__ pad_off, int* __restrict__ cursor,
    int* __restrict__ tok_of_row, float* __restrict__ gate_of_row) {
    int t = blockIdx.x * 256 + threadIdx.x;
    int e = expert_id[t];
    int p = atomicAdd(&cursor[e], 1);
    int row = pad_off[e] + p;
    tok_of_row[row] = t;
    gate_of_row[row] = gate[t];
}

// ------------- fused fp32->bf16 transpose of W1 (z<8) and W2 (z>=8) -------------
// in [z][R][C] -> out [z][C][R]; R*C = 2M for both, 512 64x64 tiles per z.
__global__ __launch_bounds__(256) void transpose_all_kernel(
    const float* __restrict__ W1, const float* __restrict__ W2,
    bf16_t* __restrict__ W1t, bf16_t* __restrict__ W2t) {
    __shared__ bf16_t tile[64][72];   // +8 pad: no pow2 bank stride
    int z = blockIdx.z;
    const float* inp; bf16_t* outp; int R, C;
    if (z < 8) { inp = W1 + (size_t)z * DDIM * HDIM; outp = W1t + (size_t)z * DDIM * HDIM;
                 R = DDIM; C = HDIM; }
    else       { inp = W2 + (size_t)(z - 8) * HDIM * DDIM; outp = W2t + (size_t)(z - 8) * HDIM * DDIM;
                 R = HDIM; C = DDIM; }
    int ctiles = C >> 6;
    int cx = blockIdx.x % ctiles, ry = blockIdx.x / ctiles;
    int r0 = ry * 64, c0 = cx * 64;
    int tid = threadIdx.x;
#pragma unroll
    for (int v = tid; v < 1024; v += 256) {     // 64x64 floats, 4/thread-iter
        int r = v >> 4, c = (v & 15) * 4;
        float4 f = *(const float4*)(inp + (size_t)(r0 + r) * C + c0 + c);
        tile[r][c + 0] = f2b(f.x); tile[r][c + 1] = f2b(f.y);
        tile[r][c + 2] = f2b(f.z); tile[r][c + 3] = f2b(f.w);
    }
    __syncthreads();
#pragma unroll
    for (int v = tid; v < 512; v += 256) {
        int c = v >> 3, r = (v & 7) * 8;
        bf16_t tmp[8];
#pragma unroll
        for (int i = 0; i < 8; i++) tmp[i] = tile[r + i][c];
        *(uint4*)(outp + (size_t)(c0 + c) * R + r0 + r) = *(uint4*)tmp;
    }
}

// ---------------- GEMM1: h[row][H] = relu(xbf[tok[row]] @ W1t[e]^T + b1[e]) ----------------
// 64x128 tile. W1t: [E][H][D]. grid (H/128, MAXT64), block 256 (4 waves, 2x2 wave grid).
__global__ __launch_bounds__(256) void gemm1_kernel(
    const bf16_t* __restrict__ x, const bf16_t* __restrict__ W1t,
    const float* __restrict__ b1, const int* __restrict__ tile_expert,
    const int* __restrict__ tok_of_row, bf16_t* __restrict__ hbuf) {
    constexpr int K = DDIM, N = HDIM;
    int tile_n = blockIdx.x, tile_m = blockIdx.y;
    int e = tile_expert[tile_m];
    if (e < 0) return;
    __shared__ bf16_t lA[64 * 64];    // 8 KiB
    __shared__ bf16_t lB[128 * 64];   // 16 KiB
    int tid = threadIdx.x, wave = tid >> 6, lane = tid & 63;
    const bf16_t* asrc[2]; const bf16_t* bsrc[4];
#pragma unroll
    for (int c = 0; c < 2; c++) {
        int rr = wave * 16 + c * 8 + (lane >> 3);
        int tok = tok_of_row[tile_m * 64 + rr];
        if (tok < 0) tok = 0;   // padded row: read any valid row; masked downstream
        asrc[c] = x + (size_t)tok * K + (lane & 7) * 8;
    }
#pragma unroll
    for (int c = 0; c < 4; c++) {
        int rr = wave * 32 + c * 8 + (lane >> 3);
        bsrc[c] = W1t + (size_t)e * N * K + (size_t)(tile_n * 128 + rr) * K + (lane & 7) * 8;
    }
    f32x4 acc[2][4];
#pragma unroll
    for (int i = 0; i < 2; i++)
#pragma unroll
        for (int j = 0; j < 4; j++) acc[i][j] = {0.f, 0.f, 0.f, 0.f};
    int wm = wave >> 1, wn = wave & 1;
    int lm = lane & 15, quad = lane >> 4;
    for (int k0 = 0; k0 < K; k0 += 64) {
        __syncthreads();
#pragma unroll
        for (int c = 0; c < 2; c++)
            gld_lds16(asrc[c] + k0, &lA[(wave * 16 + c * 8) * 64]);
#pragma unroll
        for (int c = 0; c < 4; c++)
            gld_lds16(bsrc[c] + k0, &lB[(wave * 32 + c * 8) * 64]);
        __syncthreads();
#pragma unroll
        for (int kk = 0; kk < 2; kk++) {
            short8 a[2], b[4];
#pragma unroll
            for (int i = 0; i < 2; i++)
                a[i] = *(const short8*)&lA[(wm * 32 + i * 16 + lm) * 64 + kk * 32 + quad * 8];
#pragma unroll
            for (int j = 0; j < 4; j++)
                b[j] = *(const short8*)&lB[(wn * 64 + j * 16 + lm) * 64 + kk * 32 + quad * 8];
#pragma unroll
            for (int i = 0; i < 2; i++)
#pragma unroll
                for (int j = 0; j < 4; j++)
                    acc[i][j] = __builtin_amdgcn_mfma_f32_16x16x32_bf16(a[i], b[j], acc[i][j], 0, 0, 0);
        }
    }
#pragma unroll
    for (int j = 0; j < 4; j++) {
        int col = tile_n * 128 + wn * 64 + j * 16 + lm;
        float bias = b1[e * N + col];
#pragma unroll
        for (int i = 0; i < 2; i++)
#pragma unroll
            for (int r = 0; r < 4; r++) {
                int row = tile_m * 64 + wm * 32 + i * 16 + quad * 4 + r;
                float v = acc[i][j][r] + bias;
                hbuf[(size_t)row * N + col] = f2b(fmaxf(v, 0.f));
            }
    }
}

// ---------------- GEMM2: out[tok[row]] = (h[row]@W2t[e]^T + b2[e])*gate[row] ----------------
// 64x128 tile. W2t: [E][D][H]. grid (D/128, MAXT64), block 256. fp32 scatter store.
__global__ __launch_bounds__(256) void gemm2_kernel(
    const bf16_t* __restrict__ hbuf, const bf16_t* __restrict__ W2t,
    const float* __restrict__ b2, const int* __restrict__ tile_expert,
    const int* __restrict__ tok_of_row, const float* __restrict__ gate_of_row,
    float* __restrict__ out) {
    constexpr int K = HDIM, N = DDIM;
    int tile_n = blockIdx.x, tile_m = blockIdx.y;
    int e = tile_expert[tile_m];
    if (e < 0) return;
    __shared__ bf16_t lA[64 * 64];
    __shared__ bf16_t lB[128 * 64];
    int tid = threadIdx.x, wave = tid >> 6, lane = tid & 63;
    const bf16_t* asrc[2]; const bf16_t* bsrc[4];
#pragma unroll
    for (int c = 0; c < 2; c++) {
        int rr = wave * 16 + c * 8 + (lane >> 3);
        asrc[c] = hbuf + (size_t)(tile_m * 64 + rr) * K + (lane & 7) * 8;
    }
#pragma unroll
    for (int c = 0; c < 4; c++) {
        int rr = wave * 32 + c * 8 + (lane >> 3);
        bsrc[c] = W2t + (size_t)e * N * K + (size_t)(tile_n * 128 + rr) * K + (lane & 7) * 8;
    }
    f32x4 acc[2][4];
#pragma unroll
    for (int i = 0; i < 2; i++)
#pragma unroll
        for (int j = 0; j < 4; j++) acc[i][j] = {0.f, 0.f, 0.f, 0.f};
    int wm = wave >> 1, wn = wave & 1;
    int lm = lane & 15, quad = lane >> 4;
    for (int k0 = 0; k0 < K; k0 += 64) {
        __syncthreads();
#pragma unroll
        for (int c = 0; c < 2; c++)
            gld_lds16(asrc[c] + k0, &lA[(wave * 16 + c * 8) * 64]);
#pragma unroll
        for (int c = 0; c < 4; c++)
            gld_lds16(bsrc[c] + k0, &lB[(wave * 32 + c * 8) * 64]);
        __syncthreads();
#pragma unroll
        for (int kk = 0; kk < 2; kk++) {
            short8 a[2], b[4];
#pragma unroll
            for (int i = 0; i < 2; i++)
                a[i] = *(const short8*)&lA[(wm * 32 + i * 16 + lm) * 64 + kk * 32 + quad * 8];
#pragma unroll
            for (int j = 0; j < 4; j++)
                b[j] = *(const short8*)&lB[(wn * 64 + j * 16 + lm) * 64 + kk * 32 + quad * 8];
#pragma unroll
            for (int i = 0; i < 2; i++)
#pragma unroll
                for (int j = 0; j < 4; j++)
                    acc[i][j] = __builtin_amdgcn_mfma_f32_16x16x32_bf16(a[i], b[j], acc[i][j], 0, 0, 0);
        }
    }
#pragma unroll
    for (int j = 0; j < 4; j++) {
        int col = tile_n * 128 + wn * 64 + j * 16 + lm;
        float bias = b2[e * N + col];
#pragma unroll
        for (int i = 0; i < 2; i++)
#pragma unroll
            for (int r = 0; r < 4; r++) {
                int row = tile_m * 64 + wm * 32 + i * 16 + quad * 4 + r;
                int tok = tok_of_row[row];
                if (tok >= 0) {
                    float v = (acc[i][j][r] + bias) * gate_of_row[row];
                    out[(size_t)tok * N + col] = v;   // fp32 store
                }
            }
    }
}

extern "C" void kernel_launch(void* const* d_in, const int* in_sizes, int n_in,
                              void* d_out, int out_size, void* d_ws, size_t ws_size,
                              hipStream_t stream) {
    const float* x  = (const float*)d_in[0];
    const float* Wr = (const float*)d_in[1];
    const float* br = (const float*)d_in[2];
    const float* W1 = (const float*)d_in[3];
    const float* b1 = (const float*)d_in[4];
    const float* W2 = (const float*)d_in[5];
    const float* b2 = (const float*)d_in[6];
    float* out = (float*)d_out;
    char* ws = (char*)d_ws;

    // ws layout (bytes)
    int*    counts      = (int*)(ws + 0);        // 32 B (zeroed)
    int*    cursor      = (int*)(ws + 32);       // 32 B (zeroed)
    int*    pad_off     = (int*)(ws + 64);       // 32 B
    int*    tile_expert = (int*)(ws + 96);       // 544 B (MAXT64)
    int*    expert_id   = (int*)(ws + 1024);     // 32 KiB
    float*  gate        = (float*)(ws + 33792);  // 32 KiB
    int*    tok_of_row  = (int*)(ws + 66560);    // 34816 B
    float*  gate_of_row = (float*)(ws + 101376); // 34816 B
    bf16_t* hbuf        = (bf16_t*)(ws + 136192);    // 8704*2048*2 = 35,651,584
    bf16_t* W1t         = (bf16_t*)(ws + 35787776);  // 33,554,432
    bf16_t* W2t         = (bf16_t*)(ws + 69342208);  // 33,554,432
    bf16_t* xbf         = (bf16_t*)(ws + 102896640); // 16,777,216 -> ends 119,673,856
    // total ~120 MB

    hipMemsetAsync(counts, 0, 64, stream);   // counts + cursor

    router_kernel<<<512, 256, 0, stream>>>(x, Wr, br, expert_id, gate, counts, xbf);
    scan_kernel<<<1, 256, 0, stream>>>(counts, pad_off, tile_expert, tok_of_row);
    scatter_kernel<<<T_TOK / 256, 256, 0, stream>>>(expert_id, gate, pad_off, cursor,
                                                    tok_of_row, gate_of_row);
    transpose_all_kernel<<<dim3(512, 1, 16), 256, 0, stream>>>(W1, W2, W1t, W2t);
    gemm1_kernel<<<dim3(HDIM / 128, MAXT64), 256, 0, stream>>>(xbf, W1t, b1, tile_expert,
                                                               tok_of_row, hbuf);
    gemm2_kernel<<<dim3(DDIM / 128, MAXT64), 256, 0, stream>>>(hbuf, W2t, b2, tile_expert,
                                                               tok_of_row, gate_of_row, out);
}

// Round 6
// 389.424 us; speedup vs baseline: 1.4042x; 1.0621x over previous
//
#include <hip/hip_runtime.h>
#include <hip/hip_bf16.h>
#include <stdint.h>

// B=4 S=2048 D=1024 H=2048 E=8 ; T = 8192 tokens, top-1 MoE.
// Inputs FLOAT32, output FLOAT32; GEMM compute in bf16 MFMA (fp32 accum).
// Round 6: XOR-swizzled LDS staging in both GEMMs — kills the 16-way bank
// conflict caused by the 128B row stride that global_load_lds forces.
// LDS slot (row, s) holds source chunk s ^ (row&7); readers un-XOR.

typedef unsigned short bf16_t;
typedef short short8 __attribute__((ext_vector_type(8)));
typedef float f32x4 __attribute__((ext_vector_type(4)));

#define T_TOK 8192
#define DDIM 1024
#define HDIM 2048
#define NEXP 8
#define MAXT64 136          // sum ceil(count_e/64) <= 8192/64 + 8 = 136
#define ROWSP (MAXT64 * 64) // 8704 padded row space

__device__ __forceinline__ bf16_t f2b(float f) {
    unsigned int x = __builtin_bit_cast(unsigned int, f);
    unsigned int r = x + 0x7fffu + ((x >> 16) & 1u);   // RNE
    return (bf16_t)(r >> 16);
}
__device__ __forceinline__ void gld_lds16(const bf16_t* src, bf16_t* dst) {
    // per-lane global src, wave-uniform LDS base; lane L writes at dst + L*16B
    __builtin_amdgcn_global_load_lds((const __attribute__((address_space(1))) void*)src,
                                     (__attribute__((address_space(3))) void*)dst, 16, 0, 0);
}

// ---------------- router: Wr in VGPRs, 4 tokens/wave, fused x->bf16 ----------------
__global__ __launch_bounds__(256) void router_kernel(
    const float* __restrict__ x, const float* __restrict__ Wr,
    const float* __restrict__ br, int* __restrict__ expert_id,
    float* __restrict__ gate, int* __restrict__ counts,
    bf16_t* __restrict__ xbf) {
    __shared__ int hcnt[NEXP];
    int tid = threadIdx.x, wave = tid >> 6, lane = tid & 63;
    if (tid < NEXP) hcnt[tid] = 0;
    __syncthreads();

    float w[4][4][NEXP];
#pragma unroll
    for (int i = 0; i < 4; i++)
#pragma unroll
        for (int j = 0; j < 4; j++) {
            const float* p = Wr + (size_t)(i * 256 + lane * 4 + j) * NEXP;
            float4 a = *(const float4*)p;
            float4 b = *(const float4*)(p + 4);
            w[i][j][0] = a.x; w[i][j][1] = a.y; w[i][j][2] = a.z; w[i][j][3] = a.w;
            w[i][j][4] = b.x; w[i][j][5] = b.y; w[i][j][6] = b.z; w[i][j][7] = b.w;
        }

    int t0 = (blockIdx.x * 4 + wave) * 4;
#pragma unroll
    for (int tt = 0; tt < 4; tt++) {
        int t = t0 + tt;
        float acc[NEXP];
#pragma unroll
        for (int e = 0; e < NEXP; e++) acc[e] = 0.f;
#pragma unroll
        for (int i = 0; i < 4; i++) {
            const float* xp = x + (size_t)t * DDIM + i * 256 + lane * 4;
            float4 xv = *(const float4*)xp;
            bf16_t tmp[4] = {f2b(xv.x), f2b(xv.y), f2b(xv.z), f2b(xv.w)};
            *(uint2*)(xbf + (size_t)t * DDIM + i * 256 + lane * 4) = *(uint2*)tmp;
            float xs[4] = {xv.x, xv.y, xv.z, xv.w};
#pragma unroll
            for (int j = 0; j < 4; j++)
#pragma unroll
                for (int e = 0; e < NEXP; e++) acc[e] += xs[j] * w[i][j][e];
        }
#pragma unroll
        for (int off = 32; off; off >>= 1)
#pragma unroll
            for (int e = 0; e < NEXP; e++) acc[e] += __shfl_xor(acc[e], off);
        if (lane == 0) {
            float l[NEXP];
#pragma unroll
            for (int e = 0; e < NEXP; e++) l[e] = acc[e] + br[e];
            int best = 0; float bm = l[0];
#pragma unroll
            for (int e = 1; e < NEXP; e++) if (l[e] > bm) { bm = l[e]; best = e; }
            float s = 0.f;
#pragma unroll
            for (int e = 0; e < NEXP; e++) s += __expf(l[e] - bm);
            expert_id[t] = best;
            gate[t] = 1.0f / s;      // softmax prob of the argmax expert
            atomicAdd(&hcnt[best], 1);
        }
    }
    __syncthreads();
    if (tid < NEXP) atomicAdd(&counts[tid], hcnt[tid]);
}

// ---------------- scan: 64-aligned segment offsets + 64-tile->expert map + row init --------
__global__ __launch_bounds__(256) void scan_kernel(const int* __restrict__ counts,
                                                   int* __restrict__ pad_off,
                                                   int* __restrict__ tile_expert,
                                                   int* __restrict__ tok_of_row) {
    for (int i = threadIdx.x; i < ROWSP; i += 256) tok_of_row[i] = -1;
    if (threadIdx.x == 0) {
        int rowoff = 0, t = 0;
        for (int e = 0; e < NEXP; e++) {
            pad_off[e] = rowoff;
            int nt = (counts[e] + 63) >> 6;
            rowoff += nt << 6;
            for (int i = 0; i < nt; i++) tile_expert[t++] = e;
        }
        while (t < MAXT64) tile_expert[t++] = -1;
    }
}

// ---------------- scatter: build row->token maps ----------------
__global__ __launch_bounds__(256) void scatter_kernel(
    const int* __restrict__ expert_id, const float* __restrict__ gate,
    const int* __restrict__ pad_off, int* __restrict__ cursor,
    int* __restrict__ tok_of_row, float* __restrict__ gate_of_row) {
    int t = blockIdx.x * 256 + threadIdx.x;
    int e = expert_id[t];
    int p = atomicAdd(&cursor[e], 1);
    int row = pad_off[e] + p;
    tok_of_row[row] = t;
    gate_of_row[row] = gate[t];
}

// ------------- fused fp32->bf16 transpose of W1 (z<8) and W2 (z>=8) -------------
__global__ __launch_bounds__(256) void transpose_all_kernel(
    const float* __restrict__ W1, const float* __restrict__ W2,
    bf16_t* __restrict__ W1t, bf16_t* __restrict__ W2t) {
    __shared__ bf16_t tile[64][72];   // +8 pad: no pow2 bank stride
    int z = blockIdx.z;
    const float* inp; bf16_t* outp; int R, C;
    if (z < 8) { inp = W1 + (size_t)z * DDIM * HDIM; outp = W1t + (size_t)z * DDIM * HDIM;
                 R = DDIM; C = HDIM; }
    else       { inp = W2 + (size_t)(z - 8) * HDIM * DDIM; outp = W2t + (size_t)(z - 8) * HDIM * DDIM;
                 R = HDIM; C = DDIM; }
    int ctiles = C >> 6;
    int cx = blockIdx.x % ctiles, ry = blockIdx.x / ctiles;
    int r0 = ry * 64, c0 = cx * 64;
    int tid = threadIdx.x;
#pragma unroll
    for (int v = tid; v < 1024; v += 256) {     // 64x64 floats, 4/thread-iter
        int r = v >> 4, c = (v & 15) * 4;
        float4 f = *(const float4*)(inp + (size_t)(r0 + r) * C + c0 + c);
        tile[r][c + 0] = f2b(f.x); tile[r][c + 1] = f2b(f.y);
        tile[r][c + 2] = f2b(f.z); tile[r][c + 3] = f2b(f.w);
    }
    __syncthreads();
#pragma unroll
    for (int v = tid; v < 512; v += 256) {
        int c = v >> 3, r = (v & 7) * 8;
        bf16_t tmp[8];
#pragma unroll
        for (int i = 0; i < 8; i++) tmp[i] = tile[r + i][c];
        *(uint4*)(outp + (size_t)(c0 + c) * R + r0 + r) = *(uint4*)tmp;
    }
}

// ---------------- GEMM1: h[row][H] = relu(xbf[tok[row]] @ W1t[e]^T + b1[e]) ----------------
// 64x128 tile, XOR-swizzled LDS. W1t: [E][H][D]. grid (H/128, MAXT64), block 256.
__global__ __launch_bounds__(256) void gemm1_kernel(
    const bf16_t* __restrict__ x, const bf16_t* __restrict__ W1t,
    const float* __restrict__ b1, const int* __restrict__ tile_expert,
    const int* __restrict__ tok_of_row, bf16_t* __restrict__ hbuf) {
    constexpr int K = DDIM, N = HDIM;
    int tile_n = blockIdx.x, tile_m = blockIdx.y;
    int e = tile_expert[tile_m];
    if (e < 0) return;
    __shared__ bf16_t lA[64 * 64];    // 8 KiB
    __shared__ bf16_t lB[128 * 64];   // 16 KiB
    int tid = threadIdx.x, wave = tid >> 6, lane = tid & 63;
    // staging: lane L covers row (base + L>>3), fetches source chunk (L&7)^((L>>3)&7)
    int sc = (lane & 7) ^ ((lane >> 3) & 7);
    const bf16_t* asrc[2]; const bf16_t* bsrc[4];
#pragma unroll
    for (int c = 0; c < 2; c++) {
        int rr = wave * 16 + c * 8 + (lane >> 3);
        int tok = tok_of_row[tile_m * 64 + rr];
        if (tok < 0) tok = 0;   // padded row: read any valid row; masked downstream
        asrc[c] = x + (size_t)tok * K + sc * 8;
    }
#pragma unroll
    for (int c = 0; c < 4; c++) {
        int rr = wave * 32 + c * 8 + (lane >> 3);
        bsrc[c] = W1t + (size_t)e * N * K + (size_t)(tile_n * 128 + rr) * K + sc * 8;
    }
    f32x4 acc[2][4];
#pragma unroll
    for (int i = 0; i < 2; i++)
#pragma unroll
        for (int j = 0; j < 4; j++) acc[i][j] = {0.f, 0.f, 0.f, 0.f};
    int wm = wave >> 1, wn = wave & 1;
    int lm = lane & 15, quad = lane >> 4;
    int sw = lm & 7;   // row&7 for all fragment rows (row = mult8 + lm)
    for (int k0 = 0; k0 < K; k0 += 64) {
        __syncthreads();
#pragma unroll
        for (int c = 0; c < 2; c++)
            gld_lds16(asrc[c] + k0, &lA[(wave * 16 + c * 8) * 64]);
#pragma unroll
        for (int c = 0; c < 4; c++)
            gld_lds16(bsrc[c] + k0, &lB[(wave * 32 + c * 8) * 64]);
        __syncthreads();
#pragma unroll
        for (int kk = 0; kk < 2; kk++) {
            int slot = ((kk * 4 + quad) ^ sw) * 8;
            short8 a[2], b[4];
#pragma unroll
            for (int i = 0; i < 2; i++)
                a[i] = *(const short8*)&lA[(wm * 32 + i * 16 + lm) * 64 + slot];
#pragma unroll
            for (int j = 0; j < 4; j++)
                b[j] = *(const short8*)&lB[(wn * 64 + j * 16 + lm) * 64 + slot];
#pragma unroll
            for (int i = 0; i < 2; i++)
#pragma unroll
                for (int j = 0; j < 4; j++)
                    acc[i][j] = __builtin_amdgcn_mfma_f32_16x16x32_bf16(a[i], b[j], acc[i][j], 0, 0, 0);
        }
    }
#pragma unroll
    for (int j = 0; j < 4; j++) {
        int col = tile_n * 128 + wn * 64 + j * 16 + lm;
        float bias = b1[e * N + col];
#pragma unroll
        for (int i = 0; i < 2; i++)
#pragma unroll
            for (int r = 0; r < 4; r++) {
                int row = tile_m * 64 + wm * 32 + i * 16 + quad * 4 + r;
                float v = acc[i][j][r] + bias;
                hbuf[(size_t)row * N + col] = f2b(fmaxf(v, 0.f));
            }
    }
}

// ---------------- GEMM2: out[tok[row]] = (h[row]@W2t[e]^T + b2[e])*gate[row] ----------------
// 64x128 tile, XOR-swizzled LDS. W2t: [E][D][H]. grid (D/128, MAXT64), block 256.
__global__ __launch_bounds__(256) void gemm2_kernel(
    const bf16_t* __restrict__ hbuf, const bf16_t* __restrict__ W2t,
    const float* __restrict__ b2, const int* __restrict__ tile_expert,
    const int* __restrict__ tok_of_row, const float* __restrict__ gate_of_row,
    float* __restrict__ out) {
    constexpr int K = HDIM, N = DDIM;
    int tile_n = blockIdx.x, tile_m = blockIdx.y;
    int e = tile_expert[tile_m];
    if (e < 0) return;
    __shared__ bf16_t lA[64 * 64];
    __shared__ bf16_t lB[128 * 64];
    int tid = threadIdx.x, wave = tid >> 6, lane = tid & 63;
    int sc = (lane & 7) ^ ((lane >> 3) & 7);
    const bf16_t* asrc[2]; const bf16_t* bsrc[4];
#pragma unroll
    for (int c = 0; c < 2; c++) {
        int rr = wave * 16 + c * 8 + (lane >> 3);
        asrc[c] = hbuf + (size_t)(tile_m * 64 + rr) * K + sc * 8;
    }
#pragma unroll
    for (int c = 0; c < 4; c++) {
        int rr = wave * 32 + c * 8 + (lane >> 3);
        bsrc[c] = W2t + (size_t)e * N * K + (size_t)(tile_n * 128 + rr) * K + sc * 8;
    }
    f32x4 acc[2][4];
#pragma unroll
    for (int i = 0; i < 2; i++)
#pragma unroll
        for (int j = 0; j < 4; j++) acc[i][j] = {0.f, 0.f, 0.f, 0.f};
    int wm = wave >> 1, wn = wave & 1;
    int lm = lane & 15, quad = lane >> 4;
    int sw = lm & 7;
    for (int k0 = 0; k0 < K; k0 += 64) {
        __syncthreads();
#pragma unroll
        for (int c = 0; c < 2; c++)
            gld_lds16(asrc[c] + k0, &lA[(wave * 16 + c * 8) * 64]);
#pragma unroll
        for (int c = 0; c < 4; c++)
            gld_lds16(bsrc[c] + k0, &lB[(wave * 32 + c * 8) * 64]);
        __syncthreads();
#pragma unroll
        for (int kk = 0; kk < 2; kk++) {
            int slot = ((kk * 4 + quad) ^ sw) * 8;
            short8 a[2], b[4];
#pragma unroll
            for (int i = 0; i < 2; i++)
                a[i] = *(const short8*)&lA[(wm * 32 + i * 16 + lm) * 64 + slot];
#pragma unroll
            for (int j = 0; j < 4; j++)
                b[j] = *(const short8*)&lB[(wn * 64 + j * 16 + lm) * 64 + slot];
#pragma unroll
            for (int i = 0; i < 2; i++)
#pragma unroll
                for (int j = 0; j < 4; j++)
                    acc[i][j] = __builtin_amdgcn_mfma_f32_16x16x32_bf16(a[i], b[j], acc[i][j], 0, 0, 0);
        }
    }
#pragma unroll
    for (int j = 0; j < 4; j++) {
        int col = tile_n * 128 + wn * 64 + j * 16 + lm;
        float bias = b2[e * N + col];
#pragma unroll
        for (int i = 0; i < 2; i++)
#pragma unroll
            for (int r = 0; r < 4; r++) {
                int row = tile_m * 64 + wm * 32 + i * 16 + quad * 4 + r;
                int tok = tok_of_row[row];
                if (tok >= 0) {
                    float v = (acc[i][j][r] + bias) * gate_of_row[row];
                    out[(size_t)tok * N + col] = v;   // fp32 store
                }
            }
    }
}

extern "C" void kernel_launch(void* const* d_in, const int* in_sizes, int n_in,
                              void* d_out, int out_size, void* d_ws, size_t ws_size,
                              hipStream_t stream) {
    const float* x  = (const float*)d_in[0];
    const float* Wr = (const float*)d_in[1];
    const float* br = (const float*)d_in[2];
    const float* W1 = (const float*)d_in[3];
    const float* b1 = (const float*)d_in[4];
    const float* W2 = (const float*)d_in[5];
    const float* b2 = (const float*)d_in[6];
    float* out = (float*)d_out;
    char* ws = (char*)d_ws;

    // ws layout (bytes)
    int*    counts      = (int*)(ws + 0);        // 32 B (zeroed)
    int*    cursor      = (int*)(ws + 32);       // 32 B (zeroed)
    int*    pad_off     = (int*)(ws + 64);       // 32 B
    int*    tile_expert = (int*)(ws + 96);       // 544 B (MAXT64)
    int*    expert_id   = (int*)(ws + 1024);     // 32 KiB
    float*  gate        = (float*)(ws + 33792);  // 32 KiB
    int*    tok_of_row  = (int*)(ws + 66560);    // 34816 B
    float*  gate_of_row = (float*)(ws + 101376); // 34816 B
    bf16_t* hbuf        = (bf16_t*)(ws + 136192);    // 8704*2048*2 = 35,651,584
    bf16_t* W1t         = (bf16_t*)(ws + 35787776);  // 33,554,432
    bf16_t* W2t         = (bf16_t*)(ws + 69342208);  // 33,554,432
    bf16_t* xbf         = (bf16_t*)(ws + 102896640); // 16,777,216 -> ends 119,673,856
    // total ~120 MB

    hipMemsetAsync(counts, 0, 64, stream);   // counts + cursor

    router_kernel<<<512, 256, 0, stream>>>(x, Wr, br, expert_id, gate, counts, xbf);
    scan_kernel<<<1, 256, 0, stream>>>(counts, pad_off, tile_expert, tok_of_row);
    scatter_kernel<<<T_TOK / 256, 256, 0, stream>>>(expert_id, gate, pad_off, cursor,
                                                    tok_of_row, gate_of_row);
    transpose_all_kernel<<<dim3(512, 1, 16), 256, 0, stream>>>(W1, W2, W1t, W2t);
    gemm1_kernel<<<dim3(HDIM / 128, MAXT64), 256, 0, stream>>>(xbf, W1t, b1, tile_expert,
                                                               tok_of_row, hbuf);
    gemm2_kernel<<<dim3(DDIM / 128, MAXT64), 256, 0, stream>>>(hbuf, W2t, b2, tile_expert,
                                                               tok_of_row, gate_of_row, out);
}